// Round 7
// baseline (636.422 us; speedup 1.0000x reference)
//
#include <hip/hip_runtime.h>
#include <hip/hip_bf16.h>

#define D_MODEL 1024
#define NHEADS  16
#define DK      64
#define SEQ     2048
#define BATCH   4
#define SCALE_F 0.125f
#define NEGF    (-1e30f)
#define C2      0.1803368801111244f   /* SCALE * log2(e) */

typedef __attribute__((ext_vector_type(8))) short bf16x8;
typedef __attribute__((ext_vector_type(4))) float f32x4;
typedef __attribute__((ext_vector_type(4))) short short4v;
typedef __attribute__((ext_vector_type(2))) unsigned int uintx2;
typedef __attribute__((ext_vector_type(2), may_alias)) unsigned int uint2_ma;

#if __has_builtin(__builtin_amdgcn_exp2f)
#define EXP2(x) __builtin_amdgcn_exp2f(x)
#else
#define EXP2(x) exp2f(x)
#endif

static __device__ __forceinline__ unsigned short f2bf(float f) {
  __hip_bfloat16 h = __float2bfloat16(f);
  return __builtin_bit_cast(unsigned short, h);
}

static __device__ __forceinline__ unsigned packbf(float a, float b) {
  return (unsigned)f2bf(a) | ((unsigned)f2bf(b) << 16);
}

// ---------------------------------------------------------------- cast weights
__global__ void mha_cast_w4(const float* __restrict__ w0, const float* __restrict__ w1,
                            const float* __restrict__ w2, const float* __restrict__ w3,
                            unsigned short* __restrict__ o0, unsigned short* __restrict__ o1,
                            unsigned short* __restrict__ o2, unsigned short* __restrict__ o3) {
  int i = blockIdx.x * 256 + threadIdx.x;        // 1M threads, 4 floats each
  int j = i >> 18;                               // 256K float4 per 1024x1024 matrix
  int e = (i & 0x3FFFF) << 2;
  const float* w = (j == 0) ? w0 : (j == 1) ? w1 : (j == 2) ? w2 : w3;
  unsigned short* o = (j == 0) ? o0 : (j == 1) ? o1 : (j == 2) ? o2 : o3;
  float4 v = *(const float4*)(w + e);
  short4v r;
  r.x = (short)f2bf(v.x); r.y = (short)f2bf(v.y);
  r.z = (short)f2bf(v.z); r.w = (short)f2bf(v.w);
  *(short4v*)(o + e) = r;
}

// ------------------------------------------------- transpose x (B,D,S)->(B,S,D) bf16
__global__ void mha_transpose_cast(const float* __restrict__ x, unsigned short* __restrict__ xb) {
  __shared__ float t[32][33];
  int b = blockIdx.z;
  int s0 = blockIdx.x * 32, d0 = blockIdx.y * 32;
  int tx = threadIdx.x, ty = threadIdx.y;
#pragma unroll
  for (int i = 0; i < 4; ++i)
    t[ty + i * 8][tx] = x[((size_t)b * D_MODEL + d0 + ty + i * 8) * SEQ + s0 + tx];
  __syncthreads();
#pragma unroll
  for (int i = 0; i < 4; ++i)
    xb[((size_t)b * SEQ + s0 + ty + i * 8) * D_MODEL + d0 + tx] = f2bf(t[tx][ty + i * 8]);
}

// ---------------------------------------------------------------- GEMM (C = A * B^T)
// C[m][n] = sum_k A[m][k] * Bm[n][k]   (both operands row-major over k, K=1024)
// MODE 0: QK-proj  : m=b*S+s, n=h*64+d, bias[n], bf16 out at ((b*16+h)*S+s)*64+d
// MODE 1: V-proj^T : m=feature, n=b*S+s, bias[m], bf16 out at (b*1024+m)*S+s
// MODE 2: out-proj : same as 1 but f32 out (d_out)
template <int MODE>
__global__ __launch_bounds__(256, 2) void mha_gemm_bt(
    const unsigned short* __restrict__ A, const unsigned short* __restrict__ Bm,
    const float* __restrict__ bias, void* __restrict__ Cout) {
  __shared__ alignas(128) unsigned short lds[2 * 128 * 64];  // A tile | B tile, 32KB
  const int tid = threadIdx.x;
  const int lane = tid & 63;
  const int wave = tid >> 6;
  const int lr = lane & 15, lq = lane >> 4;
  const int m0 = blockIdx.x * 128, n0 = blockIdx.y * 128;
  const int wr = (wave >> 1) * 64, wc = (wave & 1) * 64;

  f32x4 acc[4][4] = {};

  const unsigned short* Ap = A + (size_t)m0 * 1024;
  const unsigned short* Bp = Bm + (size_t)n0 * 1024;

  int srow[4], scol[4], sdst[4];
#pragma unroll
  for (int i = 0; i < 4; ++i) {
    int c = i * 256 + tid;          // 16B chunk id, 1024 per tile
    int row = c >> 3, k8 = c & 7;
    srow[i] = row;
    scol[i] = k8 * 8;
    sdst[i] = (row * 8 + (k8 ^ (row & 7))) * 8;  // XOR-swizzled ushort index
  }

  for (int kt = 0; kt < 1024; kt += 64) {
    bf16x8 ra[4], rb[4];
#pragma unroll
    for (int i = 0; i < 4; ++i) {
      ra[i] = *(const bf16x8*)(Ap + (size_t)srow[i] * 1024 + kt + scol[i]);
      rb[i] = *(const bf16x8*)(Bp + (size_t)srow[i] * 1024 + kt + scol[i]);
    }
    __syncthreads();
#pragma unroll
    for (int i = 0; i < 4; ++i) {
      *(bf16x8*)(&lds[sdst[i]]) = ra[i];
      *(bf16x8*)(&lds[8192 + sdst[i]]) = rb[i];
    }
    __syncthreads();
#pragma unroll
    for (int ks = 0; ks < 2; ++ks) {
      bf16x8 af[4], bfr[4];
#pragma unroll
      for (int mt = 0; mt < 4; ++mt) {
        int row = wr + mt * 16 + lr;
        int us = (row * 64 + ks * 32 + lq * 8) ^ ((row & 7) << 3);
        af[mt] = *(const bf16x8*)(&lds[us]);
      }
#pragma unroll
      for (int nt = 0; nt < 4; ++nt) {
        int row = wc + nt * 16 + lr;
        int us = (row * 64 + ks * 32 + lq * 8) ^ ((row & 7) << 3);
        bfr[nt] = *(const bf16x8*)(&lds[8192 + us]);
      }
#pragma unroll
      for (int mt = 0; mt < 4; ++mt)
#pragma unroll
        for (int nt = 0; nt < 4; ++nt)
          acc[mt][nt] = __builtin_amdgcn_mfma_f32_16x16x32_bf16(af[mt], bfr[nt], acc[mt][nt], 0, 0, 0);
    }
  }

  if constexpr (MODE == 0) {
    unsigned short* C = (unsigned short*)Cout;
#pragma unroll
    for (int nt = 0; nt < 4; ++nt) {
      int n = n0 + wc + nt * 16 + lr;
      float bv = bias[n];
      int h = n >> 6, dd = n & 63;
#pragma unroll
      for (int mt = 0; mt < 4; ++mt) {
#pragma unroll
        for (int r = 0; r < 4; ++r) {
          int m = m0 + wr + mt * 16 + lq * 4 + r;
          int bb = m >> 11, s = m & 2047;
          C[((size_t)(bb * 16 + h) * SEQ + s) * 64 + dd] = f2bf(acc[mt][nt][r] + bv);
        }
      }
    }
  } else {
#pragma unroll
    for (int mt = 0; mt < 4; ++mt) {
#pragma unroll
      for (int r = 0; r < 4; ++r) {
        int m = m0 + wr + mt * 16 + lq * 4 + r;
        float bv = bias[m];
#pragma unroll
        for (int nt = 0; nt < 4; ++nt) {
          int n = n0 + wc + nt * 16 + lr;
          int bb = n >> 11, s = n & 2047;
          size_t idx = ((size_t)bb * 1024 + m) * SEQ + s;
          if constexpr (MODE == 1)
            ((unsigned short*)Cout)[idx] = f2bf(acc[mt][nt][r] + bv);
          else
            ((float*)Cout)[idx] = acc[mt][nt][r] + bv;
        }
      }
    }
  }
}

// ---------------------------------------------------------------- flash attention
// Swapped-operand structure: S^T = mfma(K,Q) so each lane owns one q-column.
// Q,K: (B,H,S,64) bf16 ; Vt: (B,H,64,S) bf16 ; ctx out: (B,S,1024) bf16
// R6: P-fragment routed in-register with TWO-register permlane swaps (verified).
// R7: __launch_bounds__(256,4) -> 4 blocks/CU (was 2; occupancy was the limiter:
// 23% occ, MfmaUtil 12%, VALUBusy 29% -> latency-stalled serial chain).
#define ATTN_BODY(KT, KBIN, KBOUT)                                                        \
  {                                                                                       \
    const int kt0 = (KT);                                                                 \
    float mb[4][4];                                                                       \
    _Pragma("unroll") for (int nt = 0; nt < 4; ++nt) {                                    \
      int4 mv = *(const int4*)(mrow + kt0 + nt * 16 + lq * 4);                            \
      mb[nt][0] = mv.x ? 0.f : NEGF; mb[nt][1] = mv.y ? 0.f : NEGF;                       \
      mb[nt][2] = mv.z ? 0.f : NEGF; mb[nt][3] = mv.w ? 0.f : NEGF;                       \
    }                                                                                     \
    bf16x8 vb[4][2];                                                                      \
    _Pragma("unroll") for (int nt = 0; nt < 4; ++nt)                                      \
      _Pragma("unroll") for (int ks = 0; ks < 2; ++ks)                                    \
        vb[nt][ks] = *(const bf16x8*)(Vb + (size_t)(nt * 16 + lr) * SEQ + kt0 + ks * 32 + lq * 8); \
    f32x4 sf[2][4];                                                                       \
    _Pragma("unroll") for (int mi = 0; mi < 2; ++mi)                                      \
      _Pragma("unroll") for (int nt = 0; nt < 4; ++nt) {                                  \
        f32x4 z = {};                                                                     \
        z = __builtin_amdgcn_mfma_f32_16x16x32_bf16(KBIN[nt * 2], aQ[mi][0], z, 0, 0, 0); \
        sf[mi][nt] = __builtin_amdgcn_mfma_f32_16x16x32_bf16(KBIN[nt * 2 + 1], aQ[mi][1], z, 0, 0, 0); \
      }                                                                                   \
    if (kt0 + 64 < SEQ) {                                                                 \
      _Pragma("unroll") for (int nt = 0; nt < 4; ++nt)                                    \
        _Pragma("unroll") for (int ks = 0; ks < 2; ++ks)                                  \
          KBOUT[nt * 2 + ks] = *(const bf16x8*)(Kb + (size_t)(kt0 + 64 + nt * 16 + lr) * DK + ks * 32 + lq * 8); \
    }                                                                                     \
    _Pragma("unroll") for (int mi = 0; mi < 2; ++mi)                                      \
      _Pragma("unroll") for (int nt = 0; nt < 4; ++nt)                                    \
        _Pragma("unroll") for (int r = 0; r < 4; ++r)                                     \
          sf[mi][nt][r] = fmaf(sf[mi][nt][r], C2, mb[nt][r]);                             \
    float tmax[2];                                                                        \
    _Pragma("unroll") for (int mi = 0; mi < 2; ++mi) {                                    \
      float a0 = fmaxf(fmaxf(sf[mi][0][0], sf[mi][0][1]), fmaxf(sf[mi][0][2], sf[mi][0][3])); \
      float a1 = fmaxf(fmaxf(sf[mi][1][0], sf[mi][1][1]), fmaxf(sf[mi][1][2], sf[mi][1][3])); \
      float a2 = fmaxf(fmaxf(sf[mi][2][0], sf[mi][2][1]), fmaxf(sf[mi][2][2], sf[mi][2][3])); \
      float a3 = fmaxf(fmaxf(sf[mi][3][0], sf[mi][3][1]), fmaxf(sf[mi][3][2], sf[mi][3][3])); \
      float t = fmaxf(fmaxf(a0, a1), fmaxf(a2, a3));                                      \
      t = fmaxf(t, __shfl_xor(t, 16));                                                    \
      t = fmaxf(t, __shfl_xor(t, 32));                                                    \
      tmax[mi] = t;                                                                       \
    }                                                                                     \
    int need = (tmax[0] > mrun[0] + 8.f) | (tmax[1] > mrun[1] + 8.f);                     \
    if (__any(need)) {                                                                    \
      _Pragma("unroll") for (int mi = 0; mi < 2; ++mi) {                                  \
        float mn = fmaxf(mrun[mi], tmax[mi]);                                             \
        float al = EXP2(mrun[mi] - mn);                                                   \
        mrun[mi] = mn;                                                                    \
        _Pragma("unroll") for (int nt = 0; nt < 4; ++nt)                                  \
          _Pragma("unroll") for (int r = 0; r < 4; ++r) o[mi][nt][r] *= al;               \
        _Pragma("unroll") for (int r = 0; r < 4; ++r) lacc[mi][r] *= al;                  \
      }                                                                                   \
    }                                                                                     \
    unsigned pkw[2][4][2];                                                                \
    _Pragma("unroll") for (int mi = 0; mi < 2; ++mi)                                      \
      _Pragma("unroll") for (int nt = 0; nt < 4; ++nt) {                                  \
        float p0 = EXP2(sf[mi][nt][0] - mrun[mi]);                                        \
        float p1 = EXP2(sf[mi][nt][1] - mrun[mi]);                                        \
        float p2 = EXP2(sf[mi][nt][2] - mrun[mi]);                                        \
        float p3 = EXP2(sf[mi][nt][3] - mrun[mi]);                                        \
        pkw[mi][nt][0] = packbf(p0, p1);                                                  \
        pkw[mi][nt][1] = packbf(p2, p3);                                                  \
      }                                                                                   \
    _Pragma("unroll") for (int mi = 0; mi < 2; ++mi)                                      \
      _Pragma("unroll") for (int ks = 0; ks < 2; ++ks) {                                  \
        uintx2 s0 = __builtin_amdgcn_permlane32_swap(pkw[mi][2 * ks][0], pkw[mi][2 * ks + 1][0], false, false); \
        uintx2 s1 = __builtin_amdgcn_permlane32_swap(pkw[mi][2 * ks][1], pkw[mi][2 * ks + 1][1], false, false); \
        uintx2 u0 = __builtin_amdgcn_permlane16_swap(s0.x, s0.y, false, false);           \
        uintx2 u1 = __builtin_amdgcn_permlane16_swap(s1.x, s1.y, false, false);           \
        uint4 fr; fr.x = u0.x; fr.y = u1.x; fr.z = u0.y; fr.w = u1.y;                     \
        bf16x8 pf = __builtin_bit_cast(bf16x8, fr);                                       \
        lacc[mi] = __builtin_amdgcn_mfma_f32_16x16x32_bf16(ones, pf, lacc[mi], 0, 0, 0);  \
        _Pragma("unroll") for (int nt = 0; nt < 4; ++nt)                                  \
          o[mi][nt] = __builtin_amdgcn_mfma_f32_16x16x32_bf16(vb[nt][ks], pf, o[mi][nt], 0, 0, 0); \
      }                                                                                   \
  }

__global__ __launch_bounds__(256, 4) void mha_attn(
    const unsigned short* __restrict__ Q, const unsigned short* __restrict__ K,
    const unsigned short* __restrict__ Vt, const int* __restrict__ mask,
    unsigned short* __restrict__ ctx) {
  const int lane = threadIdx.x & 63;
  const int wave = threadIdx.x >> 6;
  const int lr = lane & 15, lq = lane >> 4;
  const int bh = blockIdx.y, b = bh >> 4, h = bh & 15;
  const int q0 = blockIdx.x * 128 + wave * 32;

  const unsigned short* Qb = Q + (size_t)bh * SEQ * DK;
  const unsigned short* Kb = K + (size_t)bh * SEQ * DK;
  const unsigned short* Vb = Vt + (size_t)bh * DK * SEQ;
  const int* mrow = mask + b * SEQ;

  // Q fragments (B-operand): lane holds Q[q0+mi*16+lr][ks*32+lq*8 .. +7]
  bf16x8 aQ[2][2];
#pragma unroll
  for (int mi = 0; mi < 2; ++mi)
#pragma unroll
    for (int ks = 0; ks < 2; ++ks)
      aQ[mi][ks] = *(const bf16x8*)(Qb + (size_t)(q0 + mi * 16 + lr) * DK + ks * 32 + lq * 8);

  bf16x8 ones;
#pragma unroll
  for (int j = 0; j < 8; ++j) ones[j] = (short)0x3F80;

  f32x4 o[2][4] = {};
  f32x4 lacc[2] = {};
  float mrun[2] = {NEGF, NEGF};

  bf16x8 kbA[8], kbB[8];
#pragma unroll
  for (int nt = 0; nt < 4; ++nt)
#pragma unroll
    for (int ks = 0; ks < 2; ++ks)
      kbA[nt * 2 + ks] = *(const bf16x8*)(Kb + (size_t)(nt * 16 + lr) * DK + ks * 32 + lq * 8);

  for (int kt = 0; kt < SEQ; kt += 128) {
    ATTN_BODY(kt, kbA, kbB)
    ATTN_BODY(kt + 64, kbB, kbA)
  }

#pragma unroll
  for (int mi = 0; mi < 2; ++mi) {
    float dn = lacc[mi][0];
    float rl = dn > 0.f ? 1.0f / dn : 0.f;
    size_t base = ((size_t)b * SEQ + q0 + mi * 16 + lr) * D_MODEL + h * 64 + lq * 4;
#pragma unroll
    for (int nt = 0; nt < 4; ++nt) {
      uint2_ma uu;
      uu.x = packbf(o[mi][nt][0] * rl, o[mi][nt][1] * rl);
      uu.y = packbf(o[mi][nt][2] * rl, o[mi][nt][3] * rl);
      *(uint2_ma*)(ctx + base + nt * 16) = uu;
    }
  }
}

// ---------------------------------------------------------------- launcher
extern "C" void kernel_launch(void* const* d_in, const int* in_sizes, int n_in,
                              void* d_out, int out_size, void* d_ws, size_t ws_size,
                              hipStream_t stream) {
  (void)in_sizes; (void)n_in; (void)out_size; (void)ws_size;
  const float* x    = (const float*)d_in[0];
  const int*   mask = (const int*)d_in[1];
  const float* Wq   = (const float*)d_in[2];
  const float* bq   = (const float*)d_in[3];
  const float* Wk   = (const float*)d_in[4];
  const float* bk   = (const float*)d_in[5];
  const float* Wv   = (const float*)d_in[6];
  const float* bv   = (const float*)d_in[7];
  const float* Wo   = (const float*)d_in[8];
  const float* bo   = (const float*)d_in[9];
  float* out = (float*)d_out;

  // workspace layout (ushort elements): 4x 1M weights, 4x 8M activations = 72MB
  unsigned short* Wqb = (unsigned short*)d_ws;
  unsigned short* Wkb = Wqb + (1u << 20);
  unsigned short* Wvb = Wkb + (1u << 20);
  unsigned short* Wob = Wvb + (1u << 20);
  unsigned short* xb  = Wob + (1u << 20);   // (B,S,D) bf16; reused as ctx
  unsigned short* Qb  = xb + (8u << 20);
  unsigned short* Kb2 = Qb + (8u << 20);
  unsigned short* Vtb = Kb2 + (8u << 20);

  mha_cast_w4<<<4096, 256, 0, stream>>>(Wq, Wk, Wv, Wo, Wqb, Wkb, Wvb, Wob);
  mha_transpose_cast<<<dim3(64, 32, 4), dim3(32, 8), 0, stream>>>(x, xb);
  mha_gemm_bt<0><<<dim3(64, 8), 256, 0, stream>>>(xb, Wqb, bq, (void*)Qb);
  mha_gemm_bt<0><<<dim3(64, 8), 256, 0, stream>>>(xb, Wkb, bk, (void*)Kb2);
  mha_gemm_bt<1><<<dim3(8, 64), 256, 0, stream>>>(Wvb, xb, bv, (void*)Vtb);
  mha_attn<<<dim3(16, 64), 256, 0, stream>>>(Qb, Kb2, Vtb, mask, xb /*ctx*/);
  mha_gemm_bt<2><<<dim3(8, 64), 256, 0, stream>>>(Wob, xb, bo, (void*)out);
}

// Round 8
// 445.396 us; speedup vs baseline: 1.4289x; 1.4289x over previous
//
#include <hip/hip_runtime.h>
#include <hip/hip_bf16.h>

#define D_MODEL 1024
#define NHEADS  16
#define DK      64
#define SEQ     2048
#define BATCH   4
#define SCALE_F 0.125f
#define NEGF    (-1e30f)
#define C2      0.1803368801111244f   /* SCALE * log2(e) */

typedef __attribute__((ext_vector_type(8))) short bf16x8;
typedef __attribute__((ext_vector_type(4))) float f32x4;
typedef __attribute__((ext_vector_type(4))) short short4v;
typedef __attribute__((ext_vector_type(2))) unsigned int uintx2;
typedef __attribute__((ext_vector_type(2), may_alias)) unsigned int uint2_ma;

#if __has_builtin(__builtin_amdgcn_exp2f)
#define EXP2(x) __builtin_amdgcn_exp2f(x)
#else
#define EXP2(x) exp2f(x)
#endif

static __device__ __forceinline__ unsigned short f2bf(float f) {
  __hip_bfloat16 h = __float2bfloat16(f);
  return __builtin_bit_cast(unsigned short, h);
}

static __device__ __forceinline__ unsigned packbf(float a, float b) {
  return (unsigned)f2bf(a) | ((unsigned)f2bf(b) << 16);
}

// ---------------------------------------------------------------- cast weights
__global__ void mha_cast_w4(const float* __restrict__ w0, const float* __restrict__ w1,
                            const float* __restrict__ w2, const float* __restrict__ w3,
                            unsigned short* __restrict__ o0, unsigned short* __restrict__ o1,
                            unsigned short* __restrict__ o2, unsigned short* __restrict__ o3) {
  int i = blockIdx.x * 256 + threadIdx.x;        // 1M threads, 4 floats each
  int j = i >> 18;                               // 256K float4 per 1024x1024 matrix
  int e = (i & 0x3FFFF) << 2;
  const float* w = (j == 0) ? w0 : (j == 1) ? w1 : (j == 2) ? w2 : w3;
  unsigned short* o = (j == 0) ? o0 : (j == 1) ? o1 : (j == 2) ? o2 : o3;
  float4 v = *(const float4*)(w + e);
  short4v r;
  r.x = (short)f2bf(v.x); r.y = (short)f2bf(v.y);
  r.z = (short)f2bf(v.z); r.w = (short)f2bf(v.w);
  *(short4v*)(o + e) = r;
}

// ------------------------------------------------- transpose x (B,D,S)->(B,S,D) bf16
__global__ void mha_transpose_cast(const float* __restrict__ x, unsigned short* __restrict__ xb) {
  __shared__ float t[32][33];
  int b = blockIdx.z;
  int s0 = blockIdx.x * 32, d0 = blockIdx.y * 32;
  int tx = threadIdx.x, ty = threadIdx.y;
#pragma unroll
  for (int i = 0; i < 4; ++i)
    t[ty + i * 8][tx] = x[((size_t)b * D_MODEL + d0 + ty + i * 8) * SEQ + s0 + tx];
  __syncthreads();
#pragma unroll
  for (int i = 0; i < 4; ++i)
    xb[((size_t)b * SEQ + s0 + ty + i * 8) * D_MODEL + d0 + tx] = f2bf(t[tx][ty + i * 8]);
}

// ---------------------------------------------------------------- GEMM (C = A * B^T)
// C[m][n] = sum_k A[m][k] * Bm[n][k]   (both operands row-major over k, K=1024)
// MODE 0: QK-proj  : m=b*S+s, n=h*64+d, bias[n], bf16 out at ((b*16+h)*S+s)*64+d
// MODE 1: V-proj^T : m=feature, n=b*S+s, bias[m], bf16 out at (b*1024+m)*S+s
// MODE 2: out-proj : same as 1 but f32 out (d_out)
template <int MODE>
__global__ __launch_bounds__(256, 2) void mha_gemm_bt(
    const unsigned short* __restrict__ A, const unsigned short* __restrict__ Bm,
    const float* __restrict__ bias, void* __restrict__ Cout) {
  __shared__ alignas(128) unsigned short lds[2 * 128 * 64];  // A tile | B tile, 32KB
  const int tid = threadIdx.x;
  const int lane = tid & 63;
  const int wave = tid >> 6;
  const int lr = lane & 15, lq = lane >> 4;
  const int m0 = blockIdx.x * 128, n0 = blockIdx.y * 128;
  const int wr = (wave >> 1) * 64, wc = (wave & 1) * 64;

  f32x4 acc[4][4] = {};

  const unsigned short* Ap = A + (size_t)m0 * 1024;
  const unsigned short* Bp = Bm + (size_t)n0 * 1024;

  int srow[4], scol[4], sdst[4];
#pragma unroll
  for (int i = 0; i < 4; ++i) {
    int c = i * 256 + tid;          // 16B chunk id, 1024 per tile
    int row = c >> 3, k8 = c & 7;
    srow[i] = row;
    scol[i] = k8 * 8;
    sdst[i] = (row * 8 + (k8 ^ (row & 7))) * 8;  // XOR-swizzled ushort index
  }

  for (int kt = 0; kt < 1024; kt += 64) {
    bf16x8 ra[4], rb[4];
#pragma unroll
    for (int i = 0; i < 4; ++i) {
      ra[i] = *(const bf16x8*)(Ap + (size_t)srow[i] * 1024 + kt + scol[i]);
      rb[i] = *(const bf16x8*)(Bp + (size_t)srow[i] * 1024 + kt + scol[i]);
    }
    __syncthreads();
#pragma unroll
    for (int i = 0; i < 4; ++i) {
      *(bf16x8*)(&lds[sdst[i]]) = ra[i];
      *(bf16x8*)(&lds[8192 + sdst[i]]) = rb[i];
    }
    __syncthreads();
#pragma unroll
    for (int ks = 0; ks < 2; ++ks) {
      bf16x8 af[4], bfr[4];
#pragma unroll
      for (int mt = 0; mt < 4; ++mt) {
        int row = wr + mt * 16 + lr;
        int us = (row * 64 + ks * 32 + lq * 8) ^ ((row & 7) << 3);
        af[mt] = *(const bf16x8*)(&lds[us]);
      }
#pragma unroll
      for (int nt = 0; nt < 4; ++nt) {
        int row = wc + nt * 16 + lr;
        int us = (row * 64 + ks * 32 + lq * 8) ^ ((row & 7) << 3);
        bfr[nt] = *(const bf16x8*)(&lds[8192 + us]);
      }
#pragma unroll
      for (int mt = 0; mt < 4; ++mt)
#pragma unroll
        for (int nt = 0; nt < 4; ++nt)
          acc[mt][nt] = __builtin_amdgcn_mfma_f32_16x16x32_bf16(af[mt], bfr[nt], acc[mt][nt], 0, 0, 0);
    }
  }

  if constexpr (MODE == 0) {
    unsigned short* C = (unsigned short*)Cout;
#pragma unroll
    for (int nt = 0; nt < 4; ++nt) {
      int n = n0 + wc + nt * 16 + lr;
      float bv = bias[n];
      int h = n >> 6, dd = n & 63;
#pragma unroll
      for (int mt = 0; mt < 4; ++mt) {
#pragma unroll
        for (int r = 0; r < 4; ++r) {
          int m = m0 + wr + mt * 16 + lq * 4 + r;
          int bb = m >> 11, s = m & 2047;
          C[((size_t)(bb * 16 + h) * SEQ + s) * 64 + dd] = f2bf(acc[mt][nt][r] + bv);
        }
      }
    }
  } else {
#pragma unroll
    for (int mt = 0; mt < 4; ++mt) {
#pragma unroll
      for (int r = 0; r < 4; ++r) {
        int m = m0 + wr + mt * 16 + lq * 4 + r;
        float bv = bias[m];
#pragma unroll
        for (int nt = 0; nt < 4; ++nt) {
          int n = n0 + wc + nt * 16 + lr;
          int bb = n >> 11, s = n & 2047;
          size_t idx = ((size_t)bb * 1024 + m) * SEQ + s;
          if constexpr (MODE == 1)
            ((unsigned short*)Cout)[idx] = f2bf(acc[mt][nt][r] + bv);
          else
            ((float*)Cout)[idx] = acc[mt][nt][r] + bv;
        }
      }
    }
  }
}

// ---------------------------------------------------------------- flash attention
// Swapped-operand structure: S^T = mfma(K,Q) so each lane owns one q-column.
// Q,K: (B,H,S,64) bf16 ; Vt: (B,H,64,S) bf16 ; ctx out: (B,S,1024) bf16
// R6: P-fragment routed in-register with TWO-register permlane swaps (verified).
// R8: revert R7's (256,4) [VGPR squeezed 92->64, 1.5GB scratch spill traffic].
// Drop the K register double-buffer (was 64 VGPRs) -> total footprint ~100,
// letting the HW fit 4 waves/SIMD naturally instead of 3 (R6 occ 23%).
#define ATTN_BODY(KT)                                                                     \
  {                                                                                       \
    const int kt0 = (KT);                                                                 \
    float mb[4][4];                                                                       \
    _Pragma("unroll") for (int nt = 0; nt < 4; ++nt) {                                    \
      int4 mv = *(const int4*)(mrow + kt0 + nt * 16 + lq * 4);                            \
      mb[nt][0] = mv.x ? 0.f : NEGF; mb[nt][1] = mv.y ? 0.f : NEGF;                       \
      mb[nt][2] = mv.z ? 0.f : NEGF; mb[nt][3] = mv.w ? 0.f : NEGF;                       \
    }                                                                                     \
    bf16x8 kb[8];                                                                         \
    _Pragma("unroll") for (int nt = 0; nt < 4; ++nt)                                      \
      _Pragma("unroll") for (int ks = 0; ks < 2; ++ks)                                    \
        kb[nt * 2 + ks] = *(const bf16x8*)(Kb + (size_t)(kt0 + nt * 16 + lr) * DK + ks * 32 + lq * 8); \
    bf16x8 vb[4][2];                                                                      \
    _Pragma("unroll") for (int nt = 0; nt < 4; ++nt)                                      \
      _Pragma("unroll") for (int ks = 0; ks < 2; ++ks)                                    \
        vb[nt][ks] = *(const bf16x8*)(Vb + (size_t)(nt * 16 + lr) * SEQ + kt0 + ks * 32 + lq * 8); \
    f32x4 sf[2][4];                                                                       \
    _Pragma("unroll") for (int mi = 0; mi < 2; ++mi)                                      \
      _Pragma("unroll") for (int nt = 0; nt < 4; ++nt) {                                  \
        f32x4 z = {};                                                                     \
        z = __builtin_amdgcn_mfma_f32_16x16x32_bf16(kb[nt * 2], aQ[mi][0], z, 0, 0, 0);   \
        sf[mi][nt] = __builtin_amdgcn_mfma_f32_16x16x32_bf16(kb[nt * 2 + 1], aQ[mi][1], z, 0, 0, 0); \
      }                                                                                   \
    _Pragma("unroll") for (int mi = 0; mi < 2; ++mi)                                      \
      _Pragma("unroll") for (int nt = 0; nt < 4; ++nt)                                    \
        _Pragma("unroll") for (int r = 0; r < 4; ++r)                                     \
          sf[mi][nt][r] = fmaf(sf[mi][nt][r], C2, mb[nt][r]);                             \
    float tmax[2];                                                                        \
    _Pragma("unroll") for (int mi = 0; mi < 2; ++mi) {                                    \
      float a0 = fmaxf(fmaxf(sf[mi][0][0], sf[mi][0][1]), fmaxf(sf[mi][0][2], sf[mi][0][3])); \
      float a1 = fmaxf(fmaxf(sf[mi][1][0], sf[mi][1][1]), fmaxf(sf[mi][1][2], sf[mi][1][3])); \
      float a2 = fmaxf(fmaxf(sf[mi][2][0], sf[mi][2][1]), fmaxf(sf[mi][2][2], sf[mi][2][3])); \
      float a3 = fmaxf(fmaxf(sf[mi][3][0], sf[mi][3][1]), fmaxf(sf[mi][3][2], sf[mi][3][3])); \
      float t = fmaxf(fmaxf(a0, a1), fmaxf(a2, a3));                                      \
      t = fmaxf(t, __shfl_xor(t, 16));                                                    \
      t = fmaxf(t, __shfl_xor(t, 32));                                                    \
      tmax[mi] = t;                                                                       \
    }                                                                                     \
    int need = (tmax[0] > mrun[0] + 8.f) | (tmax[1] > mrun[1] + 8.f);                     \
    if (__any(need)) {                                                                    \
      _Pragma("unroll") for (int mi = 0; mi < 2; ++mi) {                                  \
        float mn = fmaxf(mrun[mi], tmax[mi]);                                             \
        float al = EXP2(mrun[mi] - mn);                                                   \
        mrun[mi] = mn;                                                                    \
        _Pragma("unroll") for (int nt = 0; nt < 4; ++nt)                                  \
          _Pragma("unroll") for (int r = 0; r < 4; ++r) o[mi][nt][r] *= al;               \
        _Pragma("unroll") for (int r = 0; r < 4; ++r) lacc[mi][r] *= al;                  \
      }                                                                                   \
    }                                                                                     \
    unsigned pkw[2][4][2];                                                                \
    _Pragma("unroll") for (int mi = 0; mi < 2; ++mi)                                      \
      _Pragma("unroll") for (int nt = 0; nt < 4; ++nt) {                                  \
        float p0 = EXP2(sf[mi][nt][0] - mrun[mi]);                                        \
        float p1 = EXP2(sf[mi][nt][1] - mrun[mi]);                                        \
        float p2 = EXP2(sf[mi][nt][2] - mrun[mi]);                                        \
        float p3 = EXP2(sf[mi][nt][3] - mrun[mi]);                                        \
        pkw[mi][nt][0] = packbf(p0, p1);                                                  \
        pkw[mi][nt][1] = packbf(p2, p3);                                                  \
      }                                                                                   \
    _Pragma("unroll") for (int mi = 0; mi < 2; ++mi)                                      \
      _Pragma("unroll") for (int ks = 0; ks < 2; ++ks) {                                  \
        uintx2 s0 = __builtin_amdgcn_permlane32_swap(pkw[mi][2 * ks][0], pkw[mi][2 * ks + 1][0], false, false); \
        uintx2 s1 = __builtin_amdgcn_permlane32_swap(pkw[mi][2 * ks][1], pkw[mi][2 * ks + 1][1], false, false); \
        uintx2 u0 = __builtin_amdgcn_permlane16_swap(s0.x, s0.y, false, false);           \
        uintx2 u1 = __builtin_amdgcn_permlane16_swap(s1.x, s1.y, false, false);           \
        uint4 fr; fr.x = u0.x; fr.y = u1.x; fr.z = u0.y; fr.w = u1.y;                     \
        bf16x8 pf = __builtin_bit_cast(bf16x8, fr);                                       \
        lacc[mi] = __builtin_amdgcn_mfma_f32_16x16x32_bf16(ones, pf, lacc[mi], 0, 0, 0);  \
        _Pragma("unroll") for (int nt = 0; nt < 4; ++nt)                                  \
          o[mi][nt] = __builtin_amdgcn_mfma_f32_16x16x32_bf16(vb[nt][ks], pf, o[mi][nt], 0, 0, 0); \
      }                                                                                   \
  }

__global__ __launch_bounds__(256, 2) void mha_attn(
    const unsigned short* __restrict__ Q, const unsigned short* __restrict__ K,
    const unsigned short* __restrict__ Vt, const int* __restrict__ mask,
    unsigned short* __restrict__ ctx) {
  const int lane = threadIdx.x & 63;
  const int wave = threadIdx.x >> 6;
  const int lr = lane & 15, lq = lane >> 4;
  const int bh = blockIdx.y, b = bh >> 4, h = bh & 15;
  const int q0 = blockIdx.x * 128 + wave * 32;

  const unsigned short* Qb = Q + (size_t)bh * SEQ * DK;
  const unsigned short* Kb = K + (size_t)bh * SEQ * DK;
  const unsigned short* Vb = Vt + (size_t)bh * DK * SEQ;
  const int* mrow = mask + b * SEQ;

  // Q fragments (B-operand): lane holds Q[q0+mi*16+lr][ks*32+lq*8 .. +7]
  bf16x8 aQ[2][2];
#pragma unroll
  for (int mi = 0; mi < 2; ++mi)
#pragma unroll
    for (int ks = 0; ks < 2; ++ks)
      aQ[mi][ks] = *(const bf16x8*)(Qb + (size_t)(q0 + mi * 16 + lr) * DK + ks * 32 + lq * 8);

  bf16x8 ones;
#pragma unroll
  for (int j = 0; j < 8; ++j) ones[j] = (short)0x3F80;

  f32x4 o[2][4] = {};
  f32x4 lacc[2] = {};
  float mrun[2] = {NEGF, NEGF};

  for (int kt = 0; kt < SEQ; kt += 64) {
    ATTN_BODY(kt)
  }

#pragma unroll
  for (int mi = 0; mi < 2; ++mi) {
    float dn = lacc[mi][0];
    float rl = dn > 0.f ? 1.0f / dn : 0.f;
    size_t base = ((size_t)b * SEQ + q0 + mi * 16 + lr) * D_MODEL + h * 64 + lq * 4;
#pragma unroll
    for (int nt = 0; nt < 4; ++nt) {
      uint2_ma uu;
      uu.x = packbf(o[mi][nt][0] * rl, o[mi][nt][1] * rl);
      uu.y = packbf(o[mi][nt][2] * rl, o[mi][nt][3] * rl);
      *(uint2_ma*)(ctx + base + nt * 16) = uu;
    }
  }
}

// ---------------------------------------------------------------- launcher
extern "C" void kernel_launch(void* const* d_in, const int* in_sizes, int n_in,
                              void* d_out, int out_size, void* d_ws, size_t ws_size,
                              hipStream_t stream) {
  (void)in_sizes; (void)n_in; (void)out_size; (void)ws_size;
  const float* x    = (const float*)d_in[0];
  const int*   mask = (const int*)d_in[1];
  const float* Wq   = (const float*)d_in[2];
  const float* bq   = (const float*)d_in[3];
  const float* Wk   = (const float*)d_in[4];
  const float* bk   = (const float*)d_in[5];
  const float* Wv   = (const float*)d_in[6];
  const float* bv   = (const float*)d_in[7];
  const float* Wo   = (const float*)d_in[8];
  const float* bo   = (const float*)d_in[9];
  float* out = (float*)d_out;

  // workspace layout (ushort elements): 4x 1M weights, 4x 8M activations = 72MB
  unsigned short* Wqb = (unsigned short*)d_ws;
  unsigned short* Wkb = Wqb + (1u << 20);
  unsigned short* Wvb = Wkb + (1u << 20);
  unsigned short* Wob = Wvb + (1u << 20);
  unsigned short* xb  = Wob + (1u << 20);   // (B,S,D) bf16; reused as ctx
  unsigned short* Qb  = xb + (8u << 20);
  unsigned short* Kb2 = Qb + (8u << 20);
  unsigned short* Vtb = Kb2 + (8u << 20);

  mha_cast_w4<<<4096, 256, 0, stream>>>(Wq, Wk, Wv, Wo, Wqb, Wkb, Wvb, Wob);
  mha_transpose_cast<<<dim3(64, 32, 4), dim3(32, 8), 0, stream>>>(x, xb);
  mha_gemm_bt<0><<<dim3(64, 8), 256, 0, stream>>>(xb, Wqb, bq, (void*)Qb);
  mha_gemm_bt<0><<<dim3(64, 8), 256, 0, stream>>>(xb, Wkb, bk, (void*)Kb2);
  mha_gemm_bt<1><<<dim3(8, 64), 256, 0, stream>>>(Wvb, xb, bv, (void*)Vtb);
  mha_attn<<<dim3(16, 64), 256, 0, stream>>>(Qb, Kb2, Vtb, mask, xb /*ctx*/);
  mha_gemm_bt<2><<<dim3(8, 64), 256, 0, stream>>>(Wob, xb, bo, (void*)out);
}

// Round 9
// 313.987 us; speedup vs baseline: 2.0269x; 1.4185x over previous
//
#include <hip/hip_runtime.h>
#include <hip/hip_bf16.h>

#define D_MODEL 1024
#define NHEADS  16
#define DK      64
#define SEQ     2048
#define BATCH   4
#define SCALE_F 0.125f
#define NEGF    (-1e30f)
#define C2      0.1803368801111244f   /* SCALE * log2(e) */

typedef __attribute__((ext_vector_type(8))) short bf16x8;
typedef __attribute__((ext_vector_type(4))) float f32x4;
typedef __attribute__((ext_vector_type(4))) short short4v;
typedef __attribute__((ext_vector_type(2))) unsigned int uintx2;
typedef __attribute__((ext_vector_type(2), may_alias)) unsigned int uint2_ma;

#if __has_builtin(__builtin_amdgcn_exp2f)
#define EXP2(x) __builtin_amdgcn_exp2f(x)
#else
#define EXP2(x) exp2f(x)
#endif

// async global->LDS, 16B per lane; LDS dest must be wave-linear (lane*16B).
#define GLOAD16(lds_dst, g_src)                                                        \
  __builtin_amdgcn_global_load_lds(                                                    \
      (const __attribute__((address_space(1))) unsigned int*)(g_src),                  \
      (__attribute__((address_space(3))) unsigned int*)(lds_dst), 16, 0, 0)

static __device__ __forceinline__ unsigned short f2bf(float f) {
  __hip_bfloat16 h = __float2bfloat16(f);
  return __builtin_bit_cast(unsigned short, h);
}

static __device__ __forceinline__ unsigned packbf(float a, float b) {
  return (unsigned)f2bf(a) | ((unsigned)f2bf(b) << 16);
}

// ---------------------------------------------------------------- cast weights
__global__ void mha_cast_w4(const float* __restrict__ w0, const float* __restrict__ w1,
                            const float* __restrict__ w2, const float* __restrict__ w3,
                            unsigned short* __restrict__ o0, unsigned short* __restrict__ o1,
                            unsigned short* __restrict__ o2, unsigned short* __restrict__ o3) {
  int i = blockIdx.x * 256 + threadIdx.x;        // 1M threads, 4 floats each
  int j = i >> 18;                               // 256K float4 per 1024x1024 matrix
  int e = (i & 0x3FFFF) << 2;
  const float* w = (j == 0) ? w0 : (j == 1) ? w1 : (j == 2) ? w2 : w3;
  unsigned short* o = (j == 0) ? o0 : (j == 1) ? o1 : (j == 2) ? o2 : o3;
  float4 v = *(const float4*)(w + e);
  short4v r;
  r.x = (short)f2bf(v.x); r.y = (short)f2bf(v.y);
  r.z = (short)f2bf(v.z); r.w = (short)f2bf(v.w);
  *(short4v*)(o + e) = r;
}

// ------------------------------------------------- transpose x (B,D,S)->(B,S,D) bf16
__global__ void mha_transpose_cast(const float* __restrict__ x, unsigned short* __restrict__ xb) {
  __shared__ float t[32][33];
  int b = blockIdx.z;
  int s0 = blockIdx.x * 32, d0 = blockIdx.y * 32;
  int tx = threadIdx.x, ty = threadIdx.y;
#pragma unroll
  for (int i = 0; i < 4; ++i)
    t[ty + i * 8][tx] = x[((size_t)b * D_MODEL + d0 + ty + i * 8) * SEQ + s0 + tx];
  __syncthreads();
#pragma unroll
  for (int i = 0; i < 4; ++i)
    xb[((size_t)b * SEQ + s0 + ty + i * 8) * D_MODEL + d0 + tx] = f2bf(t[tx][ty + i * 8]);
}

// ---------------------------------------------------------------- GEMM (C = A * B^T)
// C[m][n] = sum_k A[m][k] * Bm[n][k]   (both operands row-major over k, K=1024)
// MODE 0: QK-proj  : m=b*S+s, n=h*64+d, bias[n], bf16 out at ((b*16+h)*S+s)*64+d
// MODE 1: V-proj^T : m=feature, n=b*S+s, bias[m], bf16 out at (b*1024+m)*S+s
// MODE 2: out-proj : same as 1 but f32 out (d_out)
template <int MODE>
__global__ __launch_bounds__(256, 2) void mha_gemm_bt(
    const unsigned short* __restrict__ A, const unsigned short* __restrict__ Bm,
    const float* __restrict__ bias, void* __restrict__ Cout) {
  __shared__ alignas(128) unsigned short lds[2 * 128 * 64];  // A tile | B tile, 32KB
  const int tid = threadIdx.x;
  const int lane = tid & 63;
  const int wave = tid >> 6;
  const int lr = lane & 15, lq = lane >> 4;
  const int m0 = blockIdx.x * 128, n0 = blockIdx.y * 128;
  const int wr = (wave >> 1) * 64, wc = (wave & 1) * 64;

  f32x4 acc[4][4] = {};

  const unsigned short* Ap = A + (size_t)m0 * 1024;
  const unsigned short* Bp = Bm + (size_t)n0 * 1024;

  int srow[4], scol[4], sdst[4];
#pragma unroll
  for (int i = 0; i < 4; ++i) {
    int c = i * 256 + tid;          // 16B chunk id, 1024 per tile
    int row = c >> 3, k8 = c & 7;
    srow[i] = row;
    scol[i] = k8 * 8;
    sdst[i] = (row * 8 + (k8 ^ (row & 7))) * 8;  // XOR-swizzled ushort index
  }

  for (int kt = 0; kt < 1024; kt += 64) {
    bf16x8 ra[4], rb[4];
#pragma unroll
    for (int i = 0; i < 4; ++i) {
      ra[i] = *(const bf16x8*)(Ap + (size_t)srow[i] * 1024 + kt + scol[i]);
      rb[i] = *(const bf16x8*)(Bp + (size_t)srow[i] * 1024 + kt + scol[i]);
    }
    __syncthreads();
#pragma unroll
    for (int i = 0; i < 4; ++i) {
      *(bf16x8*)(&lds[sdst[i]]) = ra[i];
      *(bf16x8*)(&lds[8192 + sdst[i]]) = rb[i];
    }
    __syncthreads();
#pragma unroll
    for (int ks = 0; ks < 2; ++ks) {
      bf16x8 af[4], bfr[4];
#pragma unroll
      for (int mt = 0; mt < 4; ++mt) {
        int row = wr + mt * 16 + lr;
        int us = (row * 64 + ks * 32 + lq * 8) ^ ((row & 7) << 3);
        af[mt] = *(const bf16x8*)(&lds[us]);
      }
#pragma unroll
      for (int nt = 0; nt < 4; ++nt) {
        int row = wc + nt * 16 + lr;
        int us = (row * 64 + ks * 32 + lq * 8) ^ ((row & 7) << 3);
        bfr[nt] = *(const bf16x8*)(&lds[8192 + us]);
      }
#pragma unroll
      for (int mt = 0; mt < 4; ++mt)
#pragma unroll
        for (int nt = 0; nt < 4; ++nt)
          acc[mt][nt] = __builtin_amdgcn_mfma_f32_16x16x32_bf16(af[mt], bfr[nt], acc[mt][nt], 0, 0, 0);
    }
  }

  if constexpr (MODE == 0) {
    unsigned short* C = (unsigned short*)Cout;
#pragma unroll
    for (int nt = 0; nt < 4; ++nt) {
      int n = n0 + wc + nt * 16 + lr;
      float bv = bias[n];
      int h = n >> 6, dd = n & 63;
#pragma unroll
      for (int mt = 0; mt < 4; ++mt) {
#pragma unroll
        for (int r = 0; r < 4; ++r) {
          int m = m0 + wr + mt * 16 + lq * 4 + r;
          int bb = m >> 11, s = m & 2047;
          C[((size_t)(bb * 16 + h) * SEQ + s) * 64 + dd] = f2bf(acc[mt][nt][r] + bv);
        }
      }
    }
  } else {
#pragma unroll
    for (int mt = 0; mt < 4; ++mt) {
#pragma unroll
      for (int r = 0; r < 4; ++r) {
        int m = m0 + wr + mt * 16 + lq * 4 + r;
        float bv = bias[m];
#pragma unroll
        for (int nt = 0; nt < 4; ++nt) {
          int n = n0 + wc + nt * 16 + lr;
          int bb = n >> 11, s = n & 2047;
          size_t idx = ((size_t)bb * 1024 + m) * SEQ + s;
          if constexpr (MODE == 1)
            ((unsigned short*)Cout)[idx] = f2bf(acc[mt][nt][r] + bv);
          else
            ((float*)Cout)[idx] = acc[mt][nt][r] + bv;
        }
      }
    }
  }
}

// ---------------------------------------------------------------- flash attention
// Swapped-operand structure: S^T = mfma(K,Q) so each lane owns one q-column.
// Q,K: (B,H,S,64) bf16 ; Vt: (B,H,64,S) bf16 ; ctx out: (B,S,1024) bf16
// R6: P-fragment routed in-register via two-register permlane swaps (verified).
// R9: K/V tiles staged in LDS ONCE per block (4 waves were each pulling the
// same 16KB/iter through L2/L3 with 16-line-divergent loads -> ~2.1GB, the
// 261us plateau). Double-buffered global_load_lds: linear LDS dest,
// inverse-XOR-swizzled per-lane SOURCE, XOR on read (rule #21). 2-way bank
// aliasing on ds_read_b128 = free.
#define ATTN_BODY(KT, CUR)                                                                \
  {                                                                                       \
    const int kt0 = (KT);                                                                 \
    float mb[4][4];                                                                       \
    _Pragma("unroll") for (int nt = 0; nt < 4; ++nt) {                                    \
      int4 mv = *(const int4*)(mrow + kt0 + nt * 16 + lq * 4);                            \
      mb[nt][0] = mv.x ? 0.f : NEGF; mb[nt][1] = mv.y ? 0.f : NEGF;                       \
      mb[nt][2] = mv.z ? 0.f : NEGF; mb[nt][3] = mv.w ? 0.f : NEGF;                       \
    }                                                                                     \
    bf16x8 kb[8];                                                                         \
    _Pragma("unroll") for (int nt = 0; nt < 4; ++nt)                                      \
      _Pragma("unroll") for (int ks = 0; ks < 2; ++ks)                                    \
        kb[nt * 2 + ks] = *(const bf16x8*)(&stile[CUR][0][(nt * 16 + lr) * 64 + (((ks * 32 + lq * 8)) ^ ((lr & 7) << 3))]); \
    bf16x8 vb[4][2];                                                                      \
    _Pragma("unroll") for (int nt = 0; nt < 4; ++nt)                                      \
      _Pragma("unroll") for (int ks = 0; ks < 2; ++ks)                                    \
        vb[nt][ks] = *(const bf16x8*)(&stile[CUR][1][(nt * 16 + lr) * 64 + (((ks * 32 + lq * 8)) ^ ((lr & 7) << 3))]); \
    f32x4 sf[2][4];                                                                       \
    _Pragma("unroll") for (int mi = 0; mi < 2; ++mi)                                      \
      _Pragma("unroll") for (int nt = 0; nt < 4; ++nt) {                                  \
        f32x4 z = {};                                                                     \
        z = __builtin_amdgcn_mfma_f32_16x16x32_bf16(kb[nt * 2], aQ[mi][0], z, 0, 0, 0);   \
        sf[mi][nt] = __builtin_amdgcn_mfma_f32_16x16x32_bf16(kb[nt * 2 + 1], aQ[mi][1], z, 0, 0, 0); \
      }                                                                                   \
    _Pragma("unroll") for (int mi = 0; mi < 2; ++mi)                                      \
      _Pragma("unroll") for (int nt = 0; nt < 4; ++nt)                                    \
        _Pragma("unroll") for (int r = 0; r < 4; ++r)                                     \
          sf[mi][nt][r] = fmaf(sf[mi][nt][r], C2, mb[nt][r]);                             \
    float tmax[2];                                                                        \
    _Pragma("unroll") for (int mi = 0; mi < 2; ++mi) {                                    \
      float a0 = fmaxf(fmaxf(sf[mi][0][0], sf[mi][0][1]), fmaxf(sf[mi][0][2], sf[mi][0][3])); \
      float a1 = fmaxf(fmaxf(sf[mi][1][0], sf[mi][1][1]), fmaxf(sf[mi][1][2], sf[mi][1][3])); \
      float a2 = fmaxf(fmaxf(sf[mi][2][0], sf[mi][2][1]), fmaxf(sf[mi][2][2], sf[mi][2][3])); \
      float a3 = fmaxf(fmaxf(sf[mi][3][0], sf[mi][3][1]), fmaxf(sf[mi][3][2], sf[mi][3][3])); \
      float t = fmaxf(fmaxf(a0, a1), fmaxf(a2, a3));                                      \
      t = fmaxf(t, __shfl_xor(t, 16));                                                    \
      t = fmaxf(t, __shfl_xor(t, 32));                                                    \
      tmax[mi] = t;                                                                       \
    }                                                                                     \
    int need = (tmax[0] > mrun[0] + 8.f) | (tmax[1] > mrun[1] + 8.f);                     \
    if (__any(need)) {                                                                    \
      _Pragma("unroll") for (int mi = 0; mi < 2; ++mi) {                                  \
        float mn = fmaxf(mrun[mi], tmax[mi]);                                             \
        float al = EXP2(mrun[mi] - mn);                                                   \
        mrun[mi] = mn;                                                                    \
        _Pragma("unroll") for (int nt = 0; nt < 4; ++nt)                                  \
          _Pragma("unroll") for (int r = 0; r < 4; ++r) o[mi][nt][r] *= al;               \
        _Pragma("unroll") for (int r = 0; r < 4; ++r) lacc[mi][r] *= al;                  \
      }                                                                                   \
    }                                                                                     \
    unsigned pkw[2][4][2];                                                                \
    _Pragma("unroll") for (int mi = 0; mi < 2; ++mi)                                      \
      _Pragma("unroll") for (int nt = 0; nt < 4; ++nt) {                                  \
        float p0 = EXP2(sf[mi][nt][0] - mrun[mi]);                                        \
        float p1 = EXP2(sf[mi][nt][1] - mrun[mi]);                                        \
        float p2 = EXP2(sf[mi][nt][2] - mrun[mi]);                                        \
        float p3 = EXP2(sf[mi][nt][3] - mrun[mi]);                                        \
        pkw[mi][nt][0] = packbf(p0, p1);                                                  \
        pkw[mi][nt][1] = packbf(p2, p3);                                                  \
      }                                                                                   \
    _Pragma("unroll") for (int mi = 0; mi < 2; ++mi)                                      \
      _Pragma("unroll") for (int ks = 0; ks < 2; ++ks) {                                  \
        uintx2 s0 = __builtin_amdgcn_permlane32_swap(pkw[mi][2 * ks][0], pkw[mi][2 * ks + 1][0], false, false); \
        uintx2 s1 = __builtin_amdgcn_permlane32_swap(pkw[mi][2 * ks][1], pkw[mi][2 * ks + 1][1], false, false); \
        uintx2 u0 = __builtin_amdgcn_permlane16_swap(s0.x, s0.y, false, false);           \
        uintx2 u1 = __builtin_amdgcn_permlane16_swap(s1.x, s1.y, false, false);           \
        uint4 fr; fr.x = u0.x; fr.y = u1.x; fr.z = u0.y; fr.w = u1.y;                     \
        bf16x8 pf = __builtin_bit_cast(bf16x8, fr);                                       \
        lacc[mi] = __builtin_amdgcn_mfma_f32_16x16x32_bf16(ones, pf, lacc[mi], 0, 0, 0);  \
        _Pragma("unroll") for (int nt = 0; nt < 4; ++nt)                                  \
          o[mi][nt] = __builtin_amdgcn_mfma_f32_16x16x32_bf16(vb[nt][ks], pf, o[mi][nt], 0, 0, 0); \
      }                                                                                   \
  }

__global__ __launch_bounds__(256, 2) void mha_attn(
    const unsigned short* __restrict__ Q, const unsigned short* __restrict__ K,
    const unsigned short* __restrict__ Vt, const int* __restrict__ mask,
    unsigned short* __restrict__ ctx) {
  __shared__ alignas(128) unsigned short stile[2][2][64 * 64];  // [buf][K|V], 32KB
  const int tid = threadIdx.x;
  const int lane = tid & 63;
  const int wave = tid >> 6;
  const int lr = lane & 15, lq = lane >> 4;
  const int bh = blockIdx.y, b = bh >> 4, h = bh & 15;
  const int q0 = blockIdx.x * 128 + wave * 32;

  const unsigned short* Qb = Q + (size_t)bh * SEQ * DK;
  const unsigned short* Kb = K + (size_t)bh * SEQ * DK;
  const unsigned short* Vb = Vt + (size_t)bh * DK * SEQ;
  const int* mrow = mask + b * SEQ;

  // staging: chunk c (16B) -> row r=c>>3, LDS col8 j=c&7 holds source col8 j^(r&7)
  int sr[2], sc[2];
#pragma unroll
  for (int i = 0; i < 2; ++i) {
    int c = tid + i * 256;
    sr[i] = c >> 3;
    sc[i] = ((c & 7) ^ ((c >> 3) & 7)) * 8;
  }
#define STAGE(BUF, KT1)                                                         \
  _Pragma("unroll") for (int i = 0; i < 2; ++i) {                               \
    int c = tid + i * 256;                                                      \
    GLOAD16(&stile[BUF][0][c * 8], Kb + (size_t)((KT1) + sr[i]) * DK + sc[i]);  \
    GLOAD16(&stile[BUF][1][c * 8], Vb + (size_t)sr[i] * SEQ + (KT1) + sc[i]);   \
  }

  // Q fragments (B-operand): lane holds Q[q0+mi*16+lr][ks*32+lq*8 .. +7]
  bf16x8 aQ[2][2];
#pragma unroll
  for (int mi = 0; mi < 2; ++mi)
#pragma unroll
    for (int ks = 0; ks < 2; ++ks)
      aQ[mi][ks] = *(const bf16x8*)(Qb + (size_t)(q0 + mi * 16 + lr) * DK + ks * 32 + lq * 8);

  bf16x8 ones;
#pragma unroll
  for (int j = 0; j < 8; ++j) ones[j] = (short)0x3F80;

  f32x4 o[2][4] = {};
  f32x4 lacc[2] = {};
  float mrun[2] = {NEGF, NEGF};

  STAGE(0, 0)
  int cur = 0;
  for (int kt = 0; kt < SEQ; kt += 64) {
    __syncthreads();                       // stage(cur) drained & visible
    if (kt + 64 < SEQ) { STAGE(cur ^ 1, kt + 64) }  // hide under compute
    ATTN_BODY(kt, cur)
    cur ^= 1;
  }

#pragma unroll
  for (int mi = 0; mi < 2; ++mi) {
    float dn = lacc[mi][0];
    float rl = dn > 0.f ? 1.0f / dn : 0.f;
    size_t base = ((size_t)b * SEQ + q0 + mi * 16 + lr) * D_MODEL + h * 64 + lq * 4;
#pragma unroll
    for (int nt = 0; nt < 4; ++nt) {
      uint2_ma uu;
      uu.x = packbf(o[mi][nt][0] * rl, o[mi][nt][1] * rl);
      uu.y = packbf(o[mi][nt][2] * rl, o[mi][nt][3] * rl);
      *(uint2_ma*)(ctx + base + nt * 16) = uu;
    }
  }
#undef STAGE
}

// ---------------------------------------------------------------- launcher
extern "C" void kernel_launch(void* const* d_in, const int* in_sizes, int n_in,
                              void* d_out, int out_size, void* d_ws, size_t ws_size,
                              hipStream_t stream) {
  (void)in_sizes; (void)n_in; (void)out_size; (void)ws_size;
  const float* x    = (const float*)d_in[0];
  const int*   mask = (const int*)d_in[1];
  const float* Wq   = (const float*)d_in[2];
  const float* bq   = (const float*)d_in[3];
  const float* Wk   = (const float*)d_in[4];
  const float* bk   = (const float*)d_in[5];
  const float* Wv   = (const float*)d_in[6];
  const float* bv   = (const float*)d_in[7];
  const float* Wo   = (const float*)d_in[8];
  const float* bo   = (const float*)d_in[9];
  float* out = (float*)d_out;

  // workspace layout (ushort elements): 4x 1M weights, 4x 8M activations = 72MB
  unsigned short* Wqb = (unsigned short*)d_ws;
  unsigned short* Wkb = Wqb + (1u << 20);
  unsigned short* Wvb = Wkb + (1u << 20);
  unsigned short* Wob = Wvb + (1u << 20);
  unsigned short* xb  = Wob + (1u << 20);   // (B,S,D) bf16; reused as ctx
  unsigned short* Qb  = xb + (8u << 20);
  unsigned short* Kb2 = Qb + (8u << 20);
  unsigned short* Vtb = Kb2 + (8u << 20);

  mha_cast_w4<<<4096, 256, 0, stream>>>(Wq, Wk, Wv, Wo, Wqb, Wkb, Wvb, Wob);
  mha_transpose_cast<<<dim3(64, 32, 4), dim3(32, 8), 0, stream>>>(x, xb);
  mha_gemm_bt<0><<<dim3(64, 8), 256, 0, stream>>>(xb, Wqb, bq, (void*)Qb);
  mha_gemm_bt<0><<<dim3(64, 8), 256, 0, stream>>>(xb, Wkb, bk, (void*)Kb2);
  mha_gemm_bt<1><<<dim3(8, 64), 256, 0, stream>>>(Wvb, xb, bv, (void*)Vtb);
  mha_attn<<<dim3(16, 64), 256, 0, stream>>>(Qb, Kb2, Vtb, mask, xb /*ctx*/);
  mha_gemm_bt<2><<<dim3(8, 64), 256, 0, stream>>>(Wob, xb, bo, (void*)out);
}